// Round 1
// baseline (2796.133 us; speedup 1.0000x reference)
//
#include <hip/hip_runtime.h>
#include <hip/hip_bf16.h>

#define N_LAYERS 2
#define D_MODEL 1024
#define D_INNER 2048
#define D_STATE 16
#define D_CONV 4
#define DT_RANK 64
#define N_CLASSES 10
#define BB 4
#define LL 1024
#define BL (BB*LL)   // 4096 rows

// ---------------- LayerNorm (D=1024, one row per block, 256 thr) -------------
__global__ __launch_bounds__(256) void layernorm_k(const float* __restrict__ x,
    const float* __restrict__ w, const float* __restrict__ b,
    float* __restrict__ out) {
  const int row = blockIdx.x;
  const int t = threadIdx.x;
  const float4 v = *(const float4*)(x + (size_t)row * D_MODEL + t * 4);
  float s = v.x + v.y + v.z + v.w;
  float q = v.x*v.x + v.y*v.y + v.z*v.z + v.w*v.w;
  #pragma unroll
  for (int o = 32; o; o >>= 1) { s += __shfl_down(s, o); q += __shfl_down(q, o); }
  __shared__ float red[8];
  if ((t & 63) == 0) { red[t >> 6] = s; red[4 + (t >> 6)] = q; }
  __syncthreads();
  s = red[0] + red[1] + red[2] + red[3];
  q = red[4] + red[5] + red[6] + red[7];
  const float mean = s * (1.f / D_MODEL);
  const float var  = q * (1.f / D_MODEL) - mean * mean;
  const float rstd = rsqrtf(var + 1e-5f);
  const float4 wv = *(const float4*)(w + t * 4);
  const float4 bv = *(const float4*)(b + t * 4);
  float4 o4;
  o4.x = (v.x - mean) * rstd * wv.x + bv.x;
  o4.y = (v.y - mean) * rstd * wv.y + bv.y;
  o4.z = (v.z - mean) * rstd * wv.z + bv.z;
  o4.w = (v.w - mean) * rstd * wv.w + bv.w;
  *(float4*)(out + (size_t)row * D_MODEL + t * 4) = o4;
}

// ---------------- fp32 SGEMM NT: C[m,n] = sum_k A[m,k]*B[n,k] (+epilogue) ----
// EPI: 0 none; 1 softplus(acc + bias[n]); 2 acc + resid[m,n]
template<int BM, int BN, int BK, int TM, int TN, int EPI>
__global__ __launch_bounds__(256) void sgemm_nt(
    const float* __restrict__ A, const float* __restrict__ B,
    float* __restrict__ C, int M, int N, int K, int lda, int ldb, int ldc,
    const float* __restrict__ bias, const float* __restrict__ resid, int ldres) {
  constexpr int THREADS = 256;
  constexpr int NT = BN / TN;           // threads along n (fast)
  constexpr int K4 = BK / 4;
  constexpr int A_F4 = BM * BK / (THREADS * 4);
  constexpr int B_F4 = BN * BK / (THREADS * 4);
  static_assert((BM / TM) * (BN / TN) == THREADS, "thread shape");
  __shared__ float As[BK][BM + 4];
  __shared__ float Bs[BK][BN + 4];
  const int tid = threadIdx.x;
  const int m0 = blockIdx.y * BM;
  const int n0 = blockIdx.x * BN;
  const int tn = (tid % NT) * TN;
  const int tm = (tid / NT) * TM;
  float acc[TM][TN] = {};
  for (int k0 = 0; k0 < K; k0 += BK) {
    #pragma unroll
    for (int i = 0; i < A_F4; i++) {
      int li = tid + i * THREADS;
      int r = li / K4, c4 = li % K4;
      float4 v = *(const float4*)(A + (size_t)(m0 + r) * lda + k0 + c4 * 4);
      As[c4*4+0][r] = v.x; As[c4*4+1][r] = v.y; As[c4*4+2][r] = v.z; As[c4*4+3][r] = v.w;
    }
    #pragma unroll
    for (int i = 0; i < B_F4; i++) {
      int li = tid + i * THREADS;
      int r = li / K4, c4 = li % K4;
      float4 v = *(const float4*)(B + (size_t)(n0 + r) * ldb + k0 + c4 * 4);
      Bs[c4*4+0][r] = v.x; Bs[c4*4+1][r] = v.y; Bs[c4*4+2][r] = v.z; Bs[c4*4+3][r] = v.w;
    }
    __syncthreads();
    #pragma unroll
    for (int k = 0; k < BK; k++) {
      float a[TM], bf[TN];
      #pragma unroll
      for (int i = 0; i < TM; i++) a[i] = As[k][tm + i];
      #pragma unroll
      for (int j = 0; j < TN; j++) bf[j] = Bs[k][tn + j];
      #pragma unroll
      for (int i = 0; i < TM; i++)
        #pragma unroll
        for (int j = 0; j < TN; j++)
          acc[i][j] = fmaf(a[i], bf[j], acc[i][j]);
    }
    __syncthreads();
  }
  #pragma unroll
  for (int i = 0; i < TM; i++) {
    const int m = m0 + tm + i;
    #pragma unroll
    for (int j = 0; j < TN; j++) {
      const int n = n0 + tn + j;
      float v = acc[i][j];
      if constexpr (EPI == 1) {
        v += bias[n];
        v = (v > 20.f) ? v : log1pf(__expf(v));
      }
      if constexpr (EPI == 2) {
        v += resid[(size_t)m * ldres + n];
      }
      C[(size_t)m * ldc + n] = v;
    }
  }
}

// ---------------- causal depthwise conv (width 4) + SiLU --------------------
__global__ __launch_bounds__(256) void conv_silu_k(const float* __restrict__ xz,
    const float* __restrict__ cw, const float* __restrict__ cb,
    float* __restrict__ xc) {
  const int gid = blockIdx.x * 256 + threadIdx.x;   // B*L*D_INNER
  const int c = gid & (D_INNER - 1);
  const int l = (gid >> 11) & (LL - 1);
  const int b = gid >> 21;
  const float4 w = *(const float4*)(cw + c * 4);
  const float* base = xz + ((size_t)(b << 10) + l) * (2 * D_INNER) + c;
  float acc = cb[c];
  acc = fmaf(w.w, base[0], acc);
  if (l >= 1) acc = fmaf(w.z, base[-(2 * D_INNER)], acc);
  if (l >= 2) acc = fmaf(w.y, base[-2 * (2 * D_INNER)], acc);
  if (l >= 3) acc = fmaf(w.x, base[-3 * (2 * D_INNER)], acc);
  xc[gid] = acc / (1.f + __expf(-acc));
}

// ---------------- selective scan: one thread per (b, channel) ---------------
__global__ __launch_bounds__(256) void scan_k(float* __restrict__ dt_y,
    const float* __restrict__ xc, const float* __restrict__ xdbl,
    const float* __restrict__ A_log, const float* __restrict__ Dp) {
  const int c = blockIdx.x * 256 + threadIdx.x;
  const int b = blockIdx.y;
  float Ac[D_STATE];
  #pragma unroll
  for (int n = 0; n < D_STATE; n++) Ac[n] = -__expf(A_log[c * D_STATE + n]);
  const float Dv = Dp[c];
  float h[D_STATE] = {};
  const size_t rb = (size_t)b * LL;
  for (int l = 0; l < LL; l++) {
    const size_t row = rb + l;
    const float dtv = dt_y[row * D_INNER + c];
    const float xv  = xc[row * D_INNER + c];
    const float* Bp = xdbl + row * 96 + DT_RANK;
    const float* Cp = Bp + D_STATE;
    const float dx = dtv * xv;
    float y = 0.f;
    #pragma unroll
    for (int n = 0; n < D_STATE; n++) {
      const float dA = __expf(dtv * Ac[n]);
      h[n] = fmaf(dA, h[n], dx * Bp[n]);
      y = fmaf(h[n], Cp[n], y);
    }
    dt_y[row * D_INNER + c] = fmaf(xv, Dv, y);
  }
}

// ---------------- gating: y *= silu(z) --------------------------------------
__global__ __launch_bounds__(256) void gate_k(float* __restrict__ y,
    const float* __restrict__ xz) {
  const int gid = blockIdx.x * 256 + threadIdx.x;
  const int c = gid & (D_INNER - 1);
  const size_t row = (size_t)(gid >> 11);
  const float z = xz[row * (2 * D_INNER) + D_INNER + c];
  y[gid] *= z / (1.f + __expf(-z));
}

// ---------------- mean pool over L ------------------------------------------
__global__ __launch_bounds__(256) void pool_k(const float* __restrict__ h,
    float* __restrict__ pooled) {
  const int d = blockIdx.x * 256 + threadIdx.x;  // 0..1023
  const int b = blockIdx.y;
  float s = 0.f;
  for (int l = 0; l < LL; l++) s += h[((size_t)(b * LL + l)) * D_MODEL + d];
  pooled[b * D_MODEL + d] = s * (1.f / LL);
}

// ---------------- classifier head --------------------------------------------
__global__ __launch_bounds__(64) void head_k(const float* __restrict__ pooled,
    const float* __restrict__ hw, const float* __restrict__ hb,
    float* __restrict__ out) {
  const int b = blockIdx.x / N_CLASSES;
  const int j = blockIdx.x % N_CLASSES;
  float s = 0.f;
  for (int k = threadIdx.x; k < D_MODEL; k += 64)
    s = fmaf(pooled[b * D_MODEL + k], hw[j * D_MODEL + k], s);
  #pragma unroll
  for (int o = 32; o; o >>= 1) s += __shfl_down(s, o);
  if (threadIdx.x == 0) out[b * N_CLASSES + j] = s + hb[j];
}

extern "C" void kernel_launch(void* const* d_in, const int* in_sizes, int n_in,
                              void* d_out, int out_size, void* d_ws, size_t ws_size,
                              hipStream_t stream) {
  const float* x0    = (const float*)d_in[0];
  const float* ln1w  = (const float*)d_in[1];
  const float* ln1b  = (const float*)d_in[2];
  const float* inw   = (const float*)d_in[3];
  const float* convw = (const float*)d_in[4];
  const float* convb = (const float*)d_in[5];
  const float* xpw   = (const float*)d_in[6];
  const float* dtpw  = (const float*)d_in[7];
  const float* dtpb  = (const float*)d_in[8];
  const float* Alog  = (const float*)d_in[9];
  const float* Dp    = (const float*)d_in[10];
  const float* outw  = (const float*)d_in[11];
  const float* normw = (const float*)d_in[12];
  const float* normb = (const float*)d_in[13];
  const float* headw = (const float*)d_in[14];
  const float* headb = (const float*)d_in[15];

  float* ws = (float*)d_ws;
  float* X      = ws;                         // 4096*1024
  float* h      = X + (size_t)BL * D_MODEL;   // 4096*1024
  float* xz     = h + (size_t)BL * D_MODEL;   // 4096*4096
  float* xc     = xz + (size_t)BL * 2 * D_INNER;  // 4096*2048
  float* xdbl   = xc + (size_t)BL * D_INNER;  // 4096*96
  float* dty    = xdbl + (size_t)BL * 96;     // 4096*2048 (dt, then y in-place)
  float* pooled = dty + (size_t)BL * D_INNER; // 4*1024

  hipMemcpyAsync(X, x0, (size_t)BL * D_MODEL * sizeof(float),
                 hipMemcpyDeviceToDevice, stream);

  for (int layer = 0; layer < N_LAYERS; ++layer) {
    layernorm_k<<<BL, 256, 0, stream>>>(X, ln1w + layer * D_MODEL,
                                        ln1b + layer * D_MODEL, h);
    // xz = h @ in_w^T : M=4096 N=4096 K=1024
    sgemm_nt<128,128,16,8,8,0><<<dim3(4096/128, 4096/128), 256, 0, stream>>>(
        h, inw + (size_t)layer * 2 * D_INNER * D_MODEL, xz,
        BL, 2 * D_INNER, D_MODEL, D_MODEL, D_MODEL, 2 * D_INNER,
        nullptr, nullptr, 0);
    conv_silu_k<<<(BL * D_INNER) / 256, 256, 0, stream>>>(
        xz, convw + layer * D_INNER * D_CONV, convb + layer * D_INNER, xc);
    // x_dbl = xc @ xp_w^T : M=4096 N=96 K=2048
    sgemm_nt<128,32,32,8,2,0><<<dim3(96/32, 4096/128), 256, 0, stream>>>(
        xc, xpw + (size_t)layer * 96 * D_INNER, xdbl,
        BL, 96, D_INNER, D_INNER, D_INNER, 96, nullptr, nullptr, 0);
    // dt = softplus(dt_r @ dtp_w^T + dtp_b) : M=4096 N=2048 K=64 (lda=96)
    sgemm_nt<128,128,16,8,8,1><<<dim3(2048/128, 4096/128), 256, 0, stream>>>(
        xdbl, dtpw + (size_t)layer * D_INNER * DT_RANK, dty,
        BL, D_INNER, DT_RANK, 96, DT_RANK, D_INNER,
        dtpb + layer * D_INNER, nullptr, 0);
    scan_k<<<dim3(D_INNER / 256, BB), 256, 0, stream>>>(
        dty, xc, xdbl, Alog + (size_t)layer * D_INNER * D_STATE,
        Dp + layer * D_INNER);
    gate_k<<<(BL * D_INNER) / 256, 256, 0, stream>>>(dty, xz);
    // X = X + y @ out_w^T : M=4096 N=1024 K=2048
    sgemm_nt<128,128,16,8,8,2><<<dim3(1024/128, 4096/128), 256, 0, stream>>>(
        dty, outw + (size_t)layer * D_MODEL * D_INNER, X,
        BL, D_MODEL, D_INNER, D_INNER, D_INNER, D_MODEL,
        nullptr, X, D_MODEL);
  }

  layernorm_k<<<BL, 256, 0, stream>>>(X, normw, normb, h);
  pool_k<<<dim3(D_MODEL / 256, BB), 256, 0, stream>>>(h, pooled);
  head_k<<<BB * N_CLASSES, 64, 0, stream>>>(pooled, headw, headb, (float*)d_out);
}